// Round 9
// baseline (1848.900 us; speedup 1.0000x reference)
//
#include <hip/hip_runtime.h>

#define B_TOT   512
#define T_LEN   512
#define F_IN_D  8
#define H_DIM   128
#define OUT_DIM 7
#define BB      2
#define NBLK    (B_TOT / BB)      // 256 blocks -> 1 per CU
#define NTHREADS 512              // 8 waves
#define SKEW    11                // layer skew (phases 0,3,6 mod 8)
#define P_TOT   (T_LEN - 1 + 2 * SKEW + 1)   // 534 pipeline steps

typedef __bf16 bf16x8 __attribute__((ext_vector_type(8)));
typedef float  f32x4  __attribute__((ext_vector_type(4)));

// xg word-offset inside a layer region: w*1040 + n16*65 + q*16 + i*4 (+r)
// (65-word row stride -> prologue stores land 2 lanes/bank = free)
#define XG_L    8320              // f32 words per layer
#define XG_W    1040              // f32 words per wave region

struct __align__(16) SharedMem {
  float  xg[3 * XG_L];            // 99840 B  xg(+bias), permuted layout, wave-private
  float  gx[3][8][2][20][4];      // 15360 B  per-step gate handoff, wave-private
  float  biasL[3][H_DIM][4];      //  6144 B  [j][gate] b_ih+b_hh
  float  z[2][H_DIM];             //  1024 B  fc1 out
  __bf16 ring[3][16][2][160];     // 30720 B  h rings: [layer][t&15][b][k] (b stride=+16 banks)
};                                 // 152.9 KB total

__device__ __forceinline__ float sigf(float x) {
  return __builtin_amdgcn_rcpf(1.f + __expf(-x));
}
__device__ __forceinline__ float tanh_fast(float x) {
  x = fminf(fmaxf(x, -15.f), 15.f);
  float e = __expf(2.f * x);
  return (e - 1.f) * __builtin_amdgcn_rcpf(e + 1.f);
}
__device__ __forceinline__ bf16x8 load8_f32_bf16(const float* p) {
  const f32x4 a = *(const f32x4*)p;
  const f32x4 b = *(const f32x4*)(p + 4);
  bf16x8 r;
  #pragma unroll
  for (int j = 0; j < 4; ++j) { r[j] = (__bf16)a[j]; r[4 + j] = (__bf16)b[j]; }
  return r;
}
__device__ __forceinline__ bf16x8 zero_bf16x8() {
  bf16x8 r;
  #pragma unroll
  for (int j = 0; j < 8; ++j) r[j] = (__bf16)0.f;
  return r;
}

// Layer-pipelined LSTM: all 3 layers run concurrently in one block, skewed by
// SKEW steps; inter-layer data flows through LDS h-rings (no global buffer).
// Serial chain: 534 pipeline steps instead of 1536.
// Gate-row permutation (R8-verified): MFMA row P=16*(w+8i)+u <-> orig W row
// 128*(u&3)+32*i+4*w+(u>>2); acc[i][r] = gate r of j=4w+q+32i, col n16 = batch.
__global__ __launch_bounds__(NTHREADS, 2)
void lstm_kernel(const float* __restrict__ x,
                 const float* __restrict__ wih0, const float* __restrict__ whh0,
                 const float* __restrict__ bih0, const float* __restrict__ bhh0,
                 const float* __restrict__ wih1, const float* __restrict__ whh1,
                 const float* __restrict__ bih1, const float* __restrict__ bhh1,
                 const float* __restrict__ wih2, const float* __restrict__ whh2,
                 const float* __restrict__ bih2, const float* __restrict__ bhh2,
                 const float* __restrict__ fc1w, const float* __restrict__ fc1b,
                 const float* __restrict__ fc2w, const float* __restrict__ fc2b,
                 float* __restrict__ out, __bf16* __restrict__ ws)
{
  __shared__ SharedMem sh;
  const int tid = threadIdx.x;
  const int w   = tid >> 6;   // wave 0..7
  const int l   = tid & 63;   // lane
  const int q   = l >> 4;     // quad
  const int n16 = l & 15;     // MFMA col = batch slot (0,1 real)
  const int bg  = blockIdx.x * BB;

  // gate-lane constants (lanes l<32): one (b, j) each
  const int gb  = l >> 4;
  const int gji = l & 15;
  const int gj  = 4 * w + (gji & 3) + 32 * (gji >> 2);

  const float* WIH[3] = {wih0, wih1, wih2};
  const float* WHH[3] = {whh0, whh1, whh2};
  const float* BIH[3] = {bih0, bih1, bih2};
  const float* BHH[3] = {bhh0, bhh1, bhh2};

  // ---- resident W_hh A-frags for ALL 3 layers (permuted rows): 192 VGPRs ----
  bf16x8 whhf[3][4][4];
  #pragma unroll
  for (int ll = 0; ll < 3; ++ll) {
    #pragma unroll
    for (int i = 0; i < 4; ++i) {
      const int ro = ((n16 & 3) << 7) + (i << 5) + (w << 2) + (n16 >> 2);
      #pragma unroll
      for (int kc = 0; kc < 4; ++kc)
        whhf[ll][i][kc] = load8_f32_bf16(WHH[ll] + ro * H_DIM + kc * 32 + q * 8);
    }
  }

  // ---- bias table ----
  if (tid < 3 * H_DIM) {
    const int ll = tid >> 7, j = tid & 127;
    #pragma unroll
    for (int r = 0; r < 4; ++r)
      sh.biasL[ll][j][r] = BIH[ll][(r << 7) + j] + BHH[ll][(r << 7) + j];
  }
  // ---- zero ring slot 15 (t=-1) for all layers ----
  for (int idx = tid; idx < 3 * 320; idx += NTHREADS)
    (&sh.ring[0][15][0][0])[(idx / 320) * 16 * 320 + (idx % 320)] = (__bf16)0.f;

  // ---- W_ih bf16 pre-pass into ws (shared region; identical-value writes) ----
  // l0 region [0,16384): per w: 4i x 64lane x 8; zeros for q!=0 (kin=8)
  #pragma unroll
  for (int i = 0; i < 4; ++i) {
    const int ro = ((n16 & 3) << 7) + (i << 5) + (w << 2) + (n16 >> 2);
    bf16x8 v = zero_bf16x8();
    if (q == 0) v = load8_f32_bf16(wih0 + ro * F_IN_D);
    *(bf16x8*)(ws + w * 2048 + i * 512 + l * 8) = v;
  }
  // l1 at 16384, l2 at 81920: per w: 4i x 4kc x 64lane x 8
  #pragma unroll
  for (int ll = 1; ll < 3; ++ll) {
    const int base = (ll == 1) ? 16384 : 81920;
    #pragma unroll
    for (int i = 0; i < 4; ++i) {
      const int ro = ((n16 & 3) << 7) + (i << 5) + (w << 2) + (n16 >> 2);
      #pragma unroll
      for (int kc = 0; kc < 4; ++kc)
        *(bf16x8*)(ws + base + w * 8192 + (i * 4 + kc) * 512 + l * 8) =
            load8_f32_bf16(WIH[ll] + ro * H_DIM + kc * 32 + q * 8);
    }
  }

  float cst[3] = {0.f, 0.f, 0.f};
  __syncthreads();   // LDS init + own ws writes drained (vmcnt) before prologue loads

  const f32x4 ZV = {0.f, 0.f, 0.f, 0.f};

  // ================= pipeline =================
  #pragma unroll 1
  for (int p = 0; p < P_TOT; ++p) {
    f32x4 acc[4];

    #pragma unroll
    for (int ll = 0; ll < 3; ++ll) {
      const int t = p - SKEW * ll;
      if (t >= 0 && t < T_LEN) {                  // wave-uniform
        // ---- chunk prologue: xg(+bias) for 8 steps, N=16 cols=(trel,b) ----
        if ((t & 7) == 0) {
          if (ll == 0) {
            bf16x8 xb = zero_bf16x8();
            if (q == 0)
              xb = load8_f32_bf16(x + ((size_t)(bg + (n16 & 1)) * T_LEN
                                       + t + (n16 >> 1)) * F_IN_D);
            #pragma unroll
            for (int i = 0; i < 4; ++i) {
              const bf16x8 wf = *(const bf16x8*)(ws + w * 2048 + i * 512 + l * 8);
              const f32x4 bi = *(const f32x4*)&sh.biasL[0][4 * w + q + 32 * i][0];
              acc[i] = __builtin_amdgcn_mfma_f32_16x16x32_bf16(wf, xb, bi, 0, 0, 0);
            }
          } else {
            const __bf16* wsl = ws + ((ll == 1) ? 16384 : 81920) + w * 8192;
            bf16x8 wf[2][4];
            #pragma unroll
            for (int i = 0; i < 4; ++i)
              wf[0][i] = *(const bf16x8*)(wsl + (i * 4) * 512 + l * 8);
            #pragma unroll
            for (int kc = 0; kc < 4; ++kc) {
              const int cur = kc & 1, nxt = cur ^ 1;
              if (kc < 3) {
                #pragma unroll
                for (int i = 0; i < 4; ++i)
                  wf[nxt][i] = *(const bf16x8*)(wsl + (i * 4 + kc + 1) * 512 + l * 8);
              }
              const bf16x8 bfr = *(const bf16x8*)
                  &sh.ring[ll - 1][(t + (n16 >> 1)) & 15][n16 & 1][kc * 32 + q * 8];
              #pragma unroll
              for (int i = 0; i < 4; ++i) {
                if (kc == 0) {
                  const f32x4 bi = *(const f32x4*)&sh.biasL[ll][4 * w + q + 32 * i][0];
                  acc[i] = __builtin_amdgcn_mfma_f32_16x16x32_bf16(wf[cur][i], bfr, bi, 0, 0, 0);
                } else {
                  acc[i] = __builtin_amdgcn_mfma_f32_16x16x32_bf16(wf[cur][i], bfr, acc[i], 0, 0, 0);
                }
              }
            }
          }
          #pragma unroll
          for (int i = 0; i < 4; ++i)
            *(f32x4*)&sh.xg[ll * XG_L + w * XG_W + n16 * 65 + q * 16 + i * 4] = acc[i];
        }

        // ---- recurrence step MFMA: W_hh x h(t-1) ----
        #pragma unroll
        for (int kc = 0; kc < 4; ++kc) {
          const bf16x8 bfr = *(const bf16x8*)
              &sh.ring[ll][(t - 1) & 15][n16 & 1][kc * 32 + q * 8];
          #pragma unroll
          for (int i = 0; i < 4; ++i) {
            if (kc == 0)
              acc[i] = __builtin_amdgcn_mfma_f32_16x16x32_bf16(whhf[ll][i][0], bfr, ZV, 0, 0, 0);
            else
              acc[i] = __builtin_amdgcn_mfma_f32_16x16x32_bf16(whhf[ll][i][kc], bfr, acc[i], 0, 0, 0);
          }
        }
        if (n16 < 2) {                 // cols 0,1 = real batch rows; b128 handoff
          #pragma unroll
          for (int i = 0; i < 4; ++i)
            *(f32x4*)&sh.gx[ll][w][n16][4 * i + q][0] = acc[i];
        }
      }
    }
    __builtin_amdgcn_wave_barrier();   // wave-private gx/xg: in-order DS (R8-verified)

    // ---- gate phase: 32 lanes/wave, one (b,j) per lane, all 3 layers ----
    if (l < 32) {
      #pragma unroll
      for (int ll = 0; ll < 3; ++ll) {
        const int t = p - SKEW * ll;
        if (t >= 0 && t < T_LEN) {
          const int s = t & 7;
          const f32x4 gv = *(const f32x4*)&sh.gx[ll][w][gb][gji][0];
          const f32x4 xv = *(const f32x4*)
              &sh.xg[ll * XG_L + w * XG_W + (2 * s + gb) * 65
                     + (gji & 3) * 16 + (gji >> 2) * 4];
          const float gi = gv[0] + xv[0], gf = gv[1] + xv[1];
          const float gg = gv[2] + xv[2], go = gv[3] + xv[3];
          cst[ll] = sigf(gf) * cst[ll] + sigf(gi) * tanh_fast(gg);
          sh.ring[ll][t & 15][gb][gj] = (__bf16)(sigf(go) * tanh_fast(cst[ll]));
        }
      }
    }
    __syncthreads();                   // h(t) visible to all waves for step t+1
  }

  // ---- FC head: final h = ring[2][511&15] ----
  if (tid < 2 * H_DIM) {
    const int bb = tid >> 7, i = tid & 127;
    float a = fc1b[i];
    #pragma unroll 8
    for (int k = 0; k < H_DIM; ++k)
      a += (float)sh.ring[2][15][bb][k] * fc1w[i * H_DIM + k];
    sh.z[bb][i] = fmaxf(a, 0.f);
  }
  __syncthreads();
  if (tid < BB * OUT_DIM) {
    const int bb = tid / OUT_DIM, o = tid % OUT_DIM;
    float a = fc2b[o];
    for (int k = 0; k < H_DIM; ++k)
      a += sh.z[bb][k] * fc2w[o * H_DIM + k];
    out[(size_t)(bg + bb) * OUT_DIM + o] = a;
  }
}

extern "C" void kernel_launch(void* const* d_in, const int* in_sizes, int n_in,
                              void* d_out, int out_size, void* d_ws, size_t ws_size,
                              hipStream_t stream) {
  const float* x    = (const float*)d_in[0];
  const float* wih0 = (const float*)d_in[1];
  const float* whh0 = (const float*)d_in[2];
  const float* bih0 = (const float*)d_in[3];
  const float* bhh0 = (const float*)d_in[4];
  const float* wih1 = (const float*)d_in[5];
  const float* whh1 = (const float*)d_in[6];
  const float* bih1 = (const float*)d_in[7];
  const float* bhh1 = (const float*)d_in[8];
  const float* wih2 = (const float*)d_in[9];
  const float* whh2 = (const float*)d_in[10];
  const float* bih2 = (const float*)d_in[11];
  const float* bhh2 = (const float*)d_in[12];
  const float* fc1w = (const float*)d_in[13];
  const float* fc1b = (const float*)d_in[14];
  const float* fc2w = (const float*)d_in[15];
  const float* fc2b = (const float*)d_in[16];
  float* out = (float*)d_out;
  __bf16* ws = (__bf16*)d_ws;   // 288 KB: pre-converted bf16 W_ih frags (shared)

  lstm_kernel<<<dim3(NBLK), dim3(NTHREADS), 0, stream>>>(
      x, wih0, whh0, bih0, bhh0, wih1, whh1, bih1, bhh1,
      wih2, whh2, bih2, bhh2, fc1w, fc1b, fc2w, fc2b, out, ws);
}

// Round 10
// 1827.747 us; speedup vs baseline: 1.0116x; 1.0116x over previous
//
#include <hip/hip_runtime.h>

#define B_TOT   512
#define T_LEN   512
#define F_IN_D  8
#define H_DIM   128
#define OUT_DIM 7
#define BB      2
#define NBLK    (B_TOT / BB)      // 256 blocks -> 1 per CU
#define NTHREADS 1024             // 16 waves
#define SKEW    11                // layer skew; prologue phases 0,3,6 (mod 8)
#define P_TOT   (T_LEN - 1 + 2 * SKEW + 1)   // 534 pipeline steps

typedef __bf16 bf16x8 __attribute__((ext_vector_type(8)));
typedef float  f32x4  __attribute__((ext_vector_type(4)));

template <int N> struct IC { static constexpr int value = N; };

struct __align__(16) SharedMem {
  float  xg[3 * 16 * 16 * 33];    // [ll][wv][plane=2*trel+b][33 words] 101376 B
  float  gx[3][16][2][9][4];      // per-step gate handoff, wave-private   13824 B
  float  biasL[3][H_DIM][4];      // [ll][j][gate] b_ih+b_hh                6144 B
  float  z[2][H_DIM];             // fc1 out                                1024 B
  __bf16 ring[3][16][2][160];     // h rings [ll][t&15][b][k] (+16-bank b) 30720 B
};                                 // 153088 B total

__device__ __forceinline__ float sigf(float x) {
  return __builtin_amdgcn_rcpf(1.f + __expf(-x));
}
__device__ __forceinline__ float tanh_fast(float x) {
  x = fminf(fmaxf(x, -15.f), 15.f);
  float e = __expf(2.f * x);
  return (e - 1.f) * __builtin_amdgcn_rcpf(e + 1.f);
}
__device__ __forceinline__ bf16x8 load8_f32_bf16(const float* p) {
  const f32x4 a = *(const f32x4*)p;
  const f32x4 b = *(const f32x4*)(p + 4);
  bf16x8 r;
  #pragma unroll
  for (int j = 0; j < 4; ++j) { r[j] = (__bf16)a[j]; r[4 + j] = (__bf16)b[j]; }
  return r;
}
__device__ __forceinline__ bf16x8 zero_bf16x8() {
  bf16x8 r;
  #pragma unroll
  for (int j = 0; j < 8; ++j) r[j] = (__bf16)0.f;
  return r;
}

// Layer-pipelined LSTM, register-feasible: 16 waves x 6 tiles (2 per layer).
// Permutation: MFMA row P = 16*(wv+16*i')+u <-> orig W row
//   128*(u&3) + 64*i' + 4*wv + (u>>2)
// => acc[i'][r] = gate r (i,f,g,o) of j = 4*wv + q + 64*i', col n16 = batch.
// Serial chain: 534 pipeline steps (vs 1536), inter-layer via LDS h-rings.
__global__ __launch_bounds__(NTHREADS, 4)   // hard cap 128 VGPR (16 waves/CU)
void lstm_kernel(const float* __restrict__ x,
                 const float* __restrict__ wih0, const float* __restrict__ whh0,
                 const float* __restrict__ bih0, const float* __restrict__ bhh0,
                 const float* __restrict__ wih1, const float* __restrict__ whh1,
                 const float* __restrict__ bih1, const float* __restrict__ bhh1,
                 const float* __restrict__ wih2, const float* __restrict__ whh2,
                 const float* __restrict__ bih2, const float* __restrict__ bhh2,
                 const float* __restrict__ fc1w, const float* __restrict__ fc1b,
                 const float* __restrict__ fc2w, const float* __restrict__ fc2b,
                 float* __restrict__ out, __bf16* __restrict__ ws)
{
  __shared__ SharedMem sh;
  const int tid = threadIdx.x;
  const int wv  = tid >> 6;   // wave 0..15
  const int l   = tid & 63;
  const int q   = l >> 4;
  const int n16 = l & 15;     // MFMA col = batch slot (0,1 real)
  const int bg  = blockIdx.x * BB;

  const float* WIH[3] = {wih0, wih1, wih2};
  const float* WHH[3] = {whh0, whh1, whh2};
  const float* BIH[3] = {bih0, bih1, bih2};
  const float* BHH[3] = {bhh0, bhh1, bhh2};

  // permuted original rows for this wave's two tiles (i' = 0,1)
  const int ro0 = ((n16 & 3) << 7) + (wv << 2) + (n16 >> 2);
  const int ro1 = ro0 + 64;

  // ---- resident W_hh A-frags: 3 layers x 2 tiles x 4 kc = 96 VGPRs ----
  bf16x8 whhf[3][2][4];
  #pragma unroll
  for (int ll = 0; ll < 3; ++ll)
    #pragma unroll
    for (int kc = 0; kc < 4; ++kc) {
      whhf[ll][0][kc] = load8_f32_bf16(WHH[ll] + ro0 * H_DIM + kc * 32 + q * 8);
      whhf[ll][1][kc] = load8_f32_bf16(WHH[ll] + ro1 * H_DIM + kc * 32 + q * 8);
    }

  // ---- W_ih bf16 pre-pass into ws (wave-private regions; benign identical race) ----
  {
    bf16x8 v0 = zero_bf16x8(), v1 = zero_bf16x8();
    if (q == 0) { v0 = load8_f32_bf16(wih0 + ro0 * F_IN_D);
                  v1 = load8_f32_bf16(wih0 + ro1 * F_IN_D); }
    *(bf16x8*)(ws + wv * 1024 + l * 8)       = v0;
    *(bf16x8*)(ws + wv * 1024 + 512 + l * 8) = v1;
    #pragma unroll
    for (int ll = 1; ll < 3; ++ll) {
      __bf16* wsl = ws + ((ll == 1) ? 16384 : 81920) + wv * 4096;
      #pragma unroll
      for (int kc = 0; kc < 4; ++kc) {
        *(bf16x8*)(wsl + kc * 512 + l * 8) =
            load8_f32_bf16(WIH[ll] + ro0 * H_DIM + kc * 32 + q * 8);
        *(bf16x8*)(wsl + (4 + kc) * 512 + l * 8) =
            load8_f32_bf16(WIH[ll] + ro1 * H_DIM + kc * 32 + q * 8);
      }
    }
  }

  // ---- bias table + ring slot 15 (t=-1) zero ----
  if (tid < 3 * H_DIM) {
    const int ll = tid >> 7, j = tid & 127;
    #pragma unroll
    for (int r = 0; r < 4; ++r)
      sh.biasL[ll][j][r] = BIH[ll][(r << 7) + j] + BHH[ll][(r << 7) + j];
  }
  if (tid < 960) {
    const int ll = tid / 320, rem = tid % 320;
    sh.ring[ll][15][rem / 160][rem % 160] = (__bf16)0.f;
  }

  float c_st = 0.f;                 // lanes l<48: cell state of (ll=l>>4, b, j)
  const int gll = l >> 4;           // gate-lane decode
  const int gb  = (l >> 3) & 1;
  const int gji = l & 7;
  const int gj  = 4 * wv + (gji & 3) + 64 * (gji >> 2);

  __syncthreads();                  // LDS init + own ws writes drained (vmcnt0)

  const f32x4 ZV = {0.f, 0.f, 0.f, 0.f};
  const int jq0 = 4 * wv + q, jq1 = jq0 + 64;   // this lane's j for i'=0,1

  // ================= pipeline: 534 serial steps =================
  #pragma unroll 1
  for (int p = 0; p < P_TOT; ++p) {

    auto do_layer = [&](auto LLC) {
      constexpr int LL = LLC.value;
      const int t = p - SKEW * LL;
      if (t < 0 || t >= T_LEN) return;
      f32x4 acc[2];

      if ((t & 7) == 0) {                        // ---- chunk prologue ----
        const f32x4 bi0 = *(const f32x4*)&sh.biasL[LL][jq0][0];
        const f32x4 bi1 = *(const f32x4*)&sh.biasL[LL][jq1][0];
        if constexpr (LL == 0) {
          bf16x8 xb = zero_bf16x8();
          if (q == 0)
            xb = load8_f32_bf16(x + ((size_t)(bg + (n16 & 1)) * T_LEN
                                     + t + (n16 >> 1)) * F_IN_D);
          const bf16x8 w0 = *(const bf16x8*)(ws + wv * 1024 + l * 8);
          const bf16x8 w1 = *(const bf16x8*)(ws + wv * 1024 + 512 + l * 8);
          acc[0] = __builtin_amdgcn_mfma_f32_16x16x32_bf16(w0, xb, bi0, 0, 0, 0);
          acc[1] = __builtin_amdgcn_mfma_f32_16x16x32_bf16(w1, xb, bi1, 0, 0, 0);
        } else {
          const __bf16* wsl = ws + ((LL == 1) ? 16384 : 81920) + wv * 4096;
          #pragma unroll
          for (int kc = 0; kc < 4; ++kc) {
            const bf16x8 w0 = *(const bf16x8*)(wsl + kc * 512 + l * 8);
            const bf16x8 w1 = *(const bf16x8*)(wsl + (4 + kc) * 512 + l * 8);
            const bf16x8 bfr = *(const bf16x8*)
                &sh.ring[LL - 1][(t + (n16 >> 1)) & 15][n16 & 1][kc * 32 + q * 8];
            acc[0] = __builtin_amdgcn_mfma_f32_16x16x32_bf16(
                w0, bfr, (kc == 0) ? bi0 : acc[0], 0, 0, 0);
            acc[1] = __builtin_amdgcn_mfma_f32_16x16x32_bf16(
                w1, bfr, (kc == 0) ? bi1 : acc[1], 0, 0, 0);
          }
        }
        float* xp = &sh.xg[((LL * 16 + wv) * 16 + n16) * 33];
        *(f32x4*)(xp + q * 4)      = acc[0];
        *(f32x4*)(xp + 16 + q * 4) = acc[1];
      }

      // ---- recurrence step: W_hh x h(t-1) ----
      #pragma unroll
      for (int kc = 0; kc < 4; ++kc) {
        const bf16x8 bfr = *(const bf16x8*)
            &sh.ring[LL][(t - 1) & 15][n16 & 1][kc * 32 + q * 8];
        acc[0] = __builtin_amdgcn_mfma_f32_16x16x32_bf16(
            whhf[LL][0][kc], bfr, (kc == 0) ? ZV : acc[0], 0, 0, 0);
        acc[1] = __builtin_amdgcn_mfma_f32_16x16x32_bf16(
            whhf[LL][1][kc], bfr, (kc == 0) ? ZV : acc[1], 0, 0, 0);
      }
      if (n16 < 2) {                 // cols 0,1 = real batch rows; b128 handoff
        *(f32x4*)&sh.gx[LL][wv][n16][q][0]     = acc[0];
        *(f32x4*)&sh.gx[LL][wv][n16][4 + q][0] = acc[1];
      }
    };
    do_layer(IC<0>{});
    do_layer(IC<1>{});
    do_layer(IC<2>{});

    __builtin_amdgcn_wave_barrier();   // wave-private gx/xg; DS in-order (R8-verified)

    if (l < 48) {                      // gate phase: one (ll,b,j) per lane
      const int t = p - SKEW * gll;
      if (t >= 0 && t < T_LEN) {
        const int s = t & 7;
        const f32x4 gv = *(const f32x4*)&sh.gx[gll][wv][gb][gji][0];
        const f32x4 xv = *(const f32x4*)
            &sh.xg[((gll * 16 + wv) * 16 + 2 * s + gb) * 33 + gji * 4];
        const float gi = gv[0] + xv[0], gf = gv[1] + xv[1];
        const float gg = gv[2] + xv[2], go = gv[3] + xv[3];
        c_st = sigf(gf) * c_st + sigf(gi) * tanh_fast(gg);
        sh.ring[gll][t & 15][gb][gj] = (__bf16)(sigf(go) * tanh_fast(c_st));
      }
    }
    __syncthreads();                   // h(t) visible to all waves for step t+1
  }

  // ---- FC head: final h = ring[2][511 & 15] ----
  if (tid < 2 * H_DIM) {
    const int bb = tid >> 7, i = tid & 127;
    float a = fc1b[i];
    #pragma unroll 8
    for (int k = 0; k < H_DIM; ++k)
      a += (float)sh.ring[2][15][bb][k] * fc1w[i * H_DIM + k];
    sh.z[bb][i] = fmaxf(a, 0.f);
  }
  __syncthreads();
  if (tid < BB * OUT_DIM) {
    const int bb = tid / OUT_DIM, o = tid % OUT_DIM;
    float a = fc2b[o];
    for (int k = 0; k < H_DIM; ++k)
      a += sh.z[bb][k] * fc2w[o * H_DIM + k];
    out[(size_t)(bg + bb) * OUT_DIM + o] = a;
  }
}

extern "C" void kernel_launch(void* const* d_in, const int* in_sizes, int n_in,
                              void* d_out, int out_size, void* d_ws, size_t ws_size,
                              hipStream_t stream) {
  const float* x    = (const float*)d_in[0];
  const float* wih0 = (const float*)d_in[1];
  const float* whh0 = (const float*)d_in[2];
  const float* bih0 = (const float*)d_in[3];
  const float* bhh0 = (const float*)d_in[4];
  const float* wih1 = (const float*)d_in[5];
  const float* whh1 = (const float*)d_in[6];
  const float* bih1 = (const float*)d_in[7];
  const float* bhh1 = (const float*)d_in[8];
  const float* wih2 = (const float*)d_in[9];
  const float* whh2 = (const float*)d_in[10];
  const float* bih2 = (const float*)d_in[11];
  const float* bhh2 = (const float*)d_in[12];
  const float* fc1w = (const float*)d_in[13];
  const float* fc1b = (const float*)d_in[14];
  const float* fc2w = (const float*)d_in[15];
  const float* fc2b = (const float*)d_in[16];
  float* out = (float*)d_out;
  __bf16* ws = (__bf16*)d_ws;   // 288 KB: pre-converted bf16 W_ih fragments

  lstm_kernel<<<dim3(NBLK), dim3(NTHREADS), 0, stream>>>(
      x, wih0, whh0, bih0, bhh0, wih1, whh1, bih1, bhh1,
      wih2, whh2, bih2, bhh2, fc1w, fc1b, fc2w, fc2b, out, ws);
}